// Round 1
// baseline (195.307 us; speedup 1.0000x reference)
//
#include <hip/hip_runtime.h>

#define LN_EPS 1e-5f
constexpr int B_ = 8;
constexpr int N_ = 10000;
constexpr int C_ = 256;   // 64 float4 per row

// ---------------- Kernel 1: partial column sums over N ----------------
// grid = B_ * nslices, block = 256. Each block sums rows [s*rps, min(N,(s+1)*rps))
// of batch b into a [C] partial row: partials[(s*B + b)*C + c].
__global__ __launch_bounds__(256) void colsum_kernel(
    const float* __restrict__ x, float* __restrict__ partials,
    int nslices, int rps)
{
    const int blk = blockIdx.x;
    const int b   = blk / nslices;
    const int s   = blk % nslices;
    const int t   = threadIdx.x;
    const int r0  = t >> 6;     // row-group 0..3
    const int c4  = t & 63;     // float4 column 0..63

    const int nStart = s * rps;
    const int nEnd   = min(N_, nStart + rps);

    const float4* xb = reinterpret_cast<const float4*>(x) + (size_t)b * N_ * 64;

    float4 acc = make_float4(0.f, 0.f, 0.f, 0.f);
    for (int n = nStart + r0; n < nEnd; n += 4) {
        float4 v = xb[(size_t)n * 64 + c4];
        acc.x += v.x; acc.y += v.y; acc.z += v.z; acc.w += v.w;
    }

    __shared__ float4 red[256];
    red[t] = acc;
    __syncthreads();
    if (t < 64) {
        float4 a0 = red[t];
        float4 a1 = red[t + 64];
        float4 a2 = red[t + 128];
        float4 a3 = red[t + 192];
        float4 sum;
        sum.x = a0.x + a1.x + a2.x + a3.x;
        sum.y = a0.y + a1.y + a2.y + a3.y;
        sum.z = a0.z + a1.z + a2.z + a3.z;
        sum.w = a0.w + a1.w + a2.w + a3.w;
        reinterpret_cast<float4*>(partials)[(size_t)(s * B_ + b) * 64 + t] = sum;
    }
}

// ---------------- Kernel 2: reduce partials -> mean, tiny GEMM -> agg ----------------
// grid = B_, block = 256 (one thread per output channel co).
// agg[b][co] = sum_ci mean[b][ci] * W[co][ci] + bias[co]
__global__ __launch_bounds__(256) void agg_kernel(
    const float* __restrict__ partials, const float* __restrict__ W,
    const float* __restrict__ bias, float* __restrict__ agg, int nslices)
{
    const int b = blockIdx.x;
    const int t = threadIdx.x;

    float sum = 0.f;
    for (int s = 0; s < nslices; ++s)
        sum += partials[(size_t)(s * B_ + b) * C_ + t];

    __shared__ float mean[C_];
    mean[t] = sum * (1.0f / (float)N_);
    __syncthreads();

    const float4* wrow = reinterpret_cast<const float4*>(W) + (size_t)t * 64;
    const float4* m4   = reinterpret_cast<const float4*>(mean);
    float acc = bias[t];
#pragma unroll 8
    for (int i = 0; i < 64; ++i) {
        float4 w = wrow[i];
        float4 m = m4[i];
        acc += w.x * m.x + w.y * m.y + w.z * m.z + w.w * m.w;
    }
    agg[b * C_ + t] = acc;
}

// ---------------- Kernel 3: residual + LayerNorm ----------------
// One wave (64 lanes) per row; lane holds float4 (4 channels). 4 rows/block.
__global__ __launch_bounds__(256) void ln_kernel(
    const float* __restrict__ x, const float* __restrict__ agg,
    const float* __restrict__ gamma, const float* __restrict__ beta,
    float* __restrict__ out)
{
    const int t    = threadIdx.x;
    const int wave = t >> 6;
    const int lane = t & 63;
    const size_t row = (size_t)blockIdx.x * 4 + wave;   // < B_*N_
    const int b = (int)(row / (size_t)N_);

    const float4* xr = reinterpret_cast<const float4*>(x) + row * 64;
    const float4* ar = reinterpret_cast<const float4*>(agg) + (size_t)b * 64;

    float4 v = xr[lane];
    float4 a = ar[lane];
    v.x += a.x; v.y += a.y; v.z += a.z; v.w += a.w;

    float s  = v.x + v.y + v.z + v.w;
    float sq = v.x * v.x + v.y * v.y + v.z * v.z + v.w * v.w;
#pragma unroll
    for (int m = 32; m >= 1; m >>= 1) {
        s  += __shfl_xor(s,  m, 64);
        sq += __shfl_xor(sq, m, 64);
    }

    const float mu  = s * (1.0f / (float)C_);
    const float var = sq * (1.0f / (float)C_) - mu * mu;
    const float rs  = rsqrtf(var + LN_EPS);

    float4 g  = reinterpret_cast<const float4*>(gamma)[lane];
    float4 be = reinterpret_cast<const float4*>(beta)[lane];

    float4 o;
    o.x = (v.x - mu) * rs * g.x + be.x;
    o.y = (v.y - mu) * rs * g.y + be.y;
    o.z = (v.z - mu) * rs * g.z + be.z;
    o.w = (v.w - mu) * rs * g.w + be.w;

    reinterpret_cast<float4*>(out)[row * 64 + lane] = o;
}

extern "C" void kernel_launch(void* const* d_in, const int* in_sizes, int n_in,
                              void* d_out, int out_size, void* d_ws, size_t ws_size,
                              hipStream_t stream) {
    const float* x     = (const float*)d_in[0];   // [B,N,C]
    const float* W     = (const float*)d_in[1];   // [C,C] (out,in)
    const float* bias  = (const float*)d_in[2];   // [C]
    const float* gamma = (const float*)d_in[3];   // [C]
    const float* beta  = (const float*)d_in[4];   // [C]
    float* out = (float*)d_out;

    // Workspace layout: [agg: B*C floats][partials: nslices*B*C floats]
    float* agg = (float*)d_ws;
    const size_t agg_bytes = (size_t)B_ * C_ * sizeof(float);
    float* partials = agg + (size_t)B_ * C_;

    const size_t slice_bytes = (size_t)B_ * C_ * sizeof(float);
    long avail = (long)ws_size - (long)agg_bytes;
    int nslices = (int)(avail / (long)slice_bytes);
    if (nslices > 100) nslices = 100;
    if (nslices < 1)   nslices = 1;
    const int rps = (N_ + nslices - 1) / nslices;   // rows per slice

    colsum_kernel<<<B_ * nslices, 256, 0, stream>>>(x, partials, nslices, rps);
    agg_kernel<<<B_, 256, 0, stream>>>(partials, W, bias, agg, nslices);
    ln_kernel<<<(B_ * N_) / 4, 256, 0, stream>>>(x, agg, gamma, beta, out);
}